// Round 2
// baseline (690.028 us; speedup 1.0000x reference)
//
#include <hip/hip_runtime.h>

constexpr int Dn  = 33;
constexpr int HSn = 1024;
constexpr int WPB = 4;   // waves per block
constexpr int RPW = 4;   // rows per wave
constexpr int CHUNKS = HSn / (WPB * RPW);  // 64 row-chunks per d

// 16-element partial dot: lane `lane` reads float4 k*64+lane of a 1024-float row.
// For fixed k, consecutive lanes read consecutive float4 -> 1 KiB coalesced.
__device__ __forceinline__ float dot16(const float4* __restrict__ row, int lane,
                                       const float4 v[4]) {
    float s = 0.f;
    #pragma unroll
    for (int k = 0; k < 4; ++k) {
        const float4 m = row[k * 64 + lane];
        s += m.x * v[k].x;
        s += m.y * v[k].y;
        s += m.z * v[k].z;
        s += m.w * v[k].w;
    }
    return s;
}

__global__ __launch_bounds__(WPB * 64)
void tmgru_kernel(const float* __restrict__ H,
                  const float* __restrict__ x,
                  const float* __restrict__ h,
                  const float* __restrict__ W_z,
                  const float* __restrict__ U_zx,
                  const float* __restrict__ U_zh,
                  const float* __restrict__ W_r,
                  const float* __restrict__ U_rx,
                  const float* __restrict__ U_rh,
                  const float* __restrict__ W_h,
                  const float* __restrict__ U_hx,
                  const float* __restrict__ U_hh,
                  const float* __restrict__ b_z,
                  const float* __restrict__ b_r,
                  const float* __restrict__ b_h,
                  float* __restrict__ out)
{
    const int lane = threadIdx.x & 63;
    const int wv   = threadIdx.x >> 6;
    const int d     = blockIdx.x / CHUNKS;
    const int chunk = blockIdx.x % CHUNKS;
    const int row0  = chunk * (WPB * RPW) + wv * RPW;

    // Stage H[d,:] and h[:] in registers: lane owns elements
    // {k*256 + 4*lane .. +4} for k in 0..3 (matches dot16's row mapping).
    float4 a[4], b[4];
    {
        const float4* Hp = (const float4*)(H + (size_t)d * HSn);
        const float4* hp = (const float4*)h;
        #pragma unroll
        for (int k = 0; k < 4; ++k) {
            a[k] = Hp[k * 64 + lane];
            b[k] = hp[k * 64 + lane];
        }
    }
    const float xd = x[d];

    for (int r = 0; r < RPW; ++r) {
        const int i = row0 + r;
        const size_t rowoff = ((size_t)d * HSn + i) * HSn;

        float s0 = dot16((const float4*)(W_z  + rowoff), lane, a);
        float s1 = dot16((const float4*)(U_zh + rowoff), lane, b);
        float s2 = dot16((const float4*)(W_r  + rowoff), lane, a);
        float s3 = dot16((const float4*)(U_rh + rowoff), lane, b);
        float s4 = dot16((const float4*)(W_h  + rowoff), lane, a);
        float s5 = dot16((const float4*)(U_hh + rowoff), lane, b);

        // Wave-64 butterfly reduction of the six dot products.
        #pragma unroll
        for (int off = 32; off > 0; off >>= 1) {
            s0 += __shfl_xor(s0, off, 64);
            s1 += __shfl_xor(s1, off, 64);
            s2 += __shfl_xor(s2, off, 64);
            s3 += __shfl_xor(s3, off, 64);
            s4 += __shfl_xor(s4, off, 64);
            s5 += __shfl_xor(s5, off, 64);
        }

        const size_t di = (size_t)d * HSn + i;
        const float z_pre = s0 + U_zx[di] * xd + s1 + b_z[i];
        const float r_pre = s2 + U_rx[di] * xd + s3 + b_r[i];
        const float zt = 1.f / (1.f + __expf(-z_pre));
        const float rt = 1.f / (1.f + __expf(-r_pre));
        const float hh = tanhf(rt * s4 + U_hx[di] * xd + s5 + b_h[i]);
        const float o  = zt * H[di] + (1.f - zt) * hh;

        if (lane == 0) out[di] = o;
    }
}

extern "C" void kernel_launch(void* const* d_in, const int* in_sizes, int n_in,
                              void* d_out, int out_size, void* d_ws, size_t ws_size,
                              hipStream_t stream) {
    const float* H    = (const float*)d_in[0];
    const float* x    = (const float*)d_in[1];
    const float* h    = (const float*)d_in[2];
    const float* W_z  = (const float*)d_in[3];
    const float* U_zx = (const float*)d_in[4];
    const float* U_zh = (const float*)d_in[5];
    const float* W_r  = (const float*)d_in[6];
    const float* U_rx = (const float*)d_in[7];
    const float* U_rh = (const float*)d_in[8];
    const float* W_h  = (const float*)d_in[9];
    const float* U_hx = (const float*)d_in[10];
    const float* U_hh = (const float*)d_in[11];
    const float* b_z  = (const float*)d_in[12];
    const float* b_r  = (const float*)d_in[13];
    const float* b_h  = (const float*)d_in[14];
    float* out = (float*)d_out;

    const int grid = Dn * CHUNKS;  // 33 * 64 = 2112 blocks
    tmgru_kernel<<<grid, WPB * 64, 0, stream>>>(
        H, x, h, W_z, U_zx, U_zh, W_r, U_rx, U_rh, W_h, U_hx, U_hh,
        b_z, b_r, b_h, out);
}